// Round 1
// baseline (866.158 us; speedup 1.0000x reference)
//
#include <hip/hip_runtime.h>

// GCN layer: out = sum_r segment_sum(vals_r * inp[src_r], dst_r) @ W_r
// Round 5: replace per-node bucket fill (51 MB scattered-line writebacks,
// 55 us) with XCD-local coarse binning (64 nodes/bin, sequential appends)
// + fused LDS-accumulator gather. GEMM path unchanged.
// N=50000, R=8, E=100000, IN=OUT=128.

constexpr int IN  = 128;
constexpr int OUT = 128;
constexpr int LDK = 136;   // padded LDS row (bf16 elems) = 272 B
constexpr int NPB = 64;    // nodes per bin (binning path)
constexpr int NXCD = 8;

typedef __attribute__((ext_vector_type(8))) short bf16x8;
typedef __attribute__((ext_vector_type(4))) float f32x4;

__device__ inline unsigned short f2bf(float f) {
    unsigned int u = __float_as_uint(f);
    u += 0x7fffu + ((u >> 16) & 1u);          // RNE
    return (unsigned short)(u >> 16);
}
__device__ inline float bflo(unsigned int u) { return __uint_as_float(u << 16); }
__device__ inline float bfhi(unsigned int u) { return __uint_as_float(u & 0xffff0000u); }

// ---------------- converts --------------------------------------------------
__global__ __launch_bounds__(256) void conv_inp_kernel(
    const float* __restrict__ x, unsigned short* __restrict__ y, int n8)
{
    const int i = blockIdx.x * 256 + threadIdx.x;
    if (i >= n8) return;
    const float4 a = ((const float4*)x)[i * 2];
    const float4 b = ((const float4*)x)[i * 2 + 1];
    uint4 o;
    o.x = (unsigned)f2bf(a.x) | ((unsigned)f2bf(a.y) << 16);
    o.y = (unsigned)f2bf(a.z) | ((unsigned)f2bf(a.w) << 16);
    o.z = (unsigned)f2bf(b.x) | ((unsigned)f2bf(b.y) << 16);
    o.w = (unsigned)f2bf(b.z) | ((unsigned)f2bf(b.w) << 16);
    ((uint4*)y)[i] = o;
}

// Wt[r][n][k] = W[r][k][n], bf16
__global__ __launch_bounds__(256) void conv_w_kernel(
    const float* __restrict__ w, unsigned short* __restrict__ wt, int total)
{
    const int t = blockIdx.x * 256 + threadIdx.x;
    if (t >= total) return;
    const int r = t >> 14, rem = t & 16383;
    const int n = rem >> 7, k = rem & 127;
    wt[t] = f2bf(w[(r << 14) + (k << 7) + n]);
}

// ---------------- MFMA GEMM: h[rel] = inp @ W[rel] --------------------------
__global__ __launch_bounds__(256) void mfma_gemm(
    const unsigned short* __restrict__ inpb,
    const unsigned short* __restrict__ wt,
    unsigned short* __restrict__ h, int rel_base, int n_nodes)
{
    __shared__ unsigned short As[128 * LDK];   // 34 KB

    const int rel = rel_base + blockIdx.y;
    const int row0 = blockIdx.x * 128;
    const int tid = threadIdx.x;
    const int wave = tid >> 6, lane = tid & 63;
    const int m = lane & 15, q = lane >> 4;

    // stage A: thread t -> row t/2, half-row (t&1)*64 elems (128 B)
    {
        const int r = tid >> 1;
        const int half = (tid & 1) * 64;
        const int grow = row0 + r;
        const uint4* gp = (const uint4*)(inpb + (size_t)grow * IN + half);
        uint4* lp = (uint4*)&As[r * LDK + half];
        #pragma unroll
        for (int i = 0; i < 8; ++i) {
            uint4 v = make_uint4(0u, 0u, 0u, 0u);
            if (grow < n_nodes) v = gp[i];
            lp[i] = v;
        }
    }

    // B fragments: b[nt][ks][j] = Wt[rel][n0+m][ks*32+q*8+j]
    bf16x8 bfrag[2][4];
    {
        const unsigned short* wtr = wt + ((size_t)rel * OUT + wave * 32) * IN;
        #pragma unroll
        for (int nt = 0; nt < 2; ++nt)
            #pragma unroll
            for (int ks = 0; ks < 4; ++ks)
                bfrag[nt][ks] = *(const bf16x8*)(
                    wtr + (size_t)(nt * 16 + m) * IN + ks * 32 + q * 8);
    }

    __syncthreads();

    f32x4 acc[8][2];
    #pragma unroll
    for (int mt = 0; mt < 8; ++mt)
        #pragma unroll
        for (int nt = 0; nt < 2; ++nt)
            acc[mt][nt] = (f32x4){0.f, 0.f, 0.f, 0.f};

    #pragma unroll
    for (int ks = 0; ks < 4; ++ks) {
        bf16x8 a[8];
        #pragma unroll
        for (int mt = 0; mt < 8; ++mt)
            a[mt] = *(const bf16x8*)&As[(mt * 16 + m) * LDK + ks * 32 + q * 8];
        #pragma unroll
        for (int mt = 0; mt < 8; ++mt) {
            acc[mt][0] = __builtin_amdgcn_mfma_f32_16x16x32_bf16(
                a[mt], bfrag[0][ks], acc[mt][0], 0, 0, 0);
            acc[mt][1] = __builtin_amdgcn_mfma_f32_16x16x32_bf16(
                a[mt], bfrag[1][ks], acc[mt][1], 0, 0, 0);
        }
    }

    unsigned short* hrel = h + (size_t)blockIdx.y * n_nodes * OUT;
    #pragma unroll
    for (int mt = 0; mt < 8; ++mt) {
        #pragma unroll
        for (int rg = 0; rg < 4; ++rg) {
            const int row = row0 + mt * 16 + q * 4 + rg;
            if (row < n_nodes) {
                unsigned short* hp = hrel + (size_t)row * OUT + wave * 32 + m;
                hp[0]  = f2bf(acc[mt][0][rg]);
                hp[16] = f2bf(acc[mt][1][rg]);
            }
        }
    }
}

// ---------------- XCD-local bin fill ----------------------------------------
// Bins of NPB=64 dst-nodes; 8 per-XCD copies so append tail lines stay in one
// L2 (appends are sequential -> full line utilization, ~6.4 MB payload vs the
// 51 MB of scattered per-node bucket writebacks).
// entry.x = (dst&63)<<19 | (rel*n_nodes+src)   [needs n_rel*n_nodes < 2^19]
// entry.y = val bits
__global__ __launch_bounds__(256) void bin_fill_kernel(
    const int* __restrict__ src, const int* __restrict__ dst,
    const float* __restrict__ vals, int* __restrict__ bin_cnt,
    int2* __restrict__ binned, int4* __restrict__ spill,
    int* __restrict__ spill_cnt, int n_edges, int n_nodes,
    int nbins, int cap, int spill_max)
{
    int xcd;
    asm volatile("s_getreg_b32 %0, hwreg(HW_REG_XCC_ID)" : "=s"(xcd));
    xcd &= (NXCD - 1);
    const int e = blockIdx.x * 256 + threadIdx.x;
    if (e >= n_edges) return;
    const size_t g = (size_t)blockIdx.y * n_edges + e;
    const int d = dst[g];
    const int enc = blockIdx.y * n_nodes + src[g];
    const int bin = d >> 6;                       // NPB = 64
    const int packed = ((d & 63) << 19) | enc;
    const int cell = xcd * nbins + bin;
    const int pos = atomicAdd(&bin_cnt[cell], 1);
    if (pos < cap) {
        binned[(size_t)cell * cap + pos] =
            make_int2(packed, __float_as_int(vals[g]));
    } else {
        const int sp = atomicAdd(spill_cnt, 1);
        if (sp < spill_max)
            spill[sp] = make_int4(d, enc, __float_as_int(vals[g]), 0);
    }
}

// ---------------- fused bin gather (LDS f32 accumulator) --------------------
// One block per bin: 64 nodes x 128 cols f32 in LDS (32 KB). 4 waves chew
// entries in chunks of 4 (4 independent h-row loads in flight); ds_add_f32
// accumulation (LDS-atomic, overlaps VMEM); coalesced 64B-chunk writeout.
__global__ __launch_bounds__(256) void bin_agg_kernel(
    const unsigned short* __restrict__ h, const int2* __restrict__ binned,
    const int* __restrict__ bin_cnt, float* __restrict__ out,
    int n_nodes, int nbins, int cap)
{
    __shared__ float accum[NPB * OUT];            // 32 KB
    const int bin = blockIdx.x;
    const int tid = threadIdx.x;
    #pragma unroll
    for (int i = 0; i < NPB * OUT / 256; ++i)
        accum[i * 256 + tid] = 0.f;
    __syncthreads();

    const int wave = tid >> 6, lane = tid & 63;
    const unsigned int* __restrict__ hw = (const unsigned int*)h;

    for (int xc = 0; xc < NXCD; ++xc) {
        const int cell = xc * nbins + bin;
        int cnt = bin_cnt[cell];
        if (cnt > cap) cnt = cap;
        const int2* __restrict__ b = binned + (size_t)cell * cap;
        for (int base = wave * 4; base < cnt; base += 16) {
            if (base + 4 <= cnt) {
                const int2 r0 = b[base],     r1 = b[base + 1];
                const int2 r2 = b[base + 2], r3 = b[base + 3];
                const unsigned int h0 = hw[(size_t)(r0.x & 0x7ffff) * 64 + lane];
                const unsigned int h1 = hw[(size_t)(r1.x & 0x7ffff) * 64 + lane];
                const unsigned int h2 = hw[(size_t)(r2.x & 0x7ffff) * 64 + lane];
                const unsigned int h3 = hw[(size_t)(r3.x & 0x7ffff) * 64 + lane];
                const float v0 = __int_as_float(r0.y), v1 = __int_as_float(r1.y);
                const float v2 = __int_as_float(r2.y), v3 = __int_as_float(r3.y);
                float* a0 = &accum[((r0.x >> 19) & 63) * OUT + 2 * lane];
                float* a1 = &accum[((r1.x >> 19) & 63) * OUT + 2 * lane];
                float* a2 = &accum[((r2.x >> 19) & 63) * OUT + 2 * lane];
                float* a3 = &accum[((r3.x >> 19) & 63) * OUT + 2 * lane];
                atomicAdd(a0,     v0 * bflo(h0));
                atomicAdd(a0 + 1, v0 * bfhi(h0));
                atomicAdd(a1,     v1 * bflo(h1));
                atomicAdd(a1 + 1, v1 * bfhi(h1));
                atomicAdd(a2,     v2 * bflo(h2));
                atomicAdd(a2 + 1, v2 * bfhi(h2));
                atomicAdd(a3,     v3 * bflo(h3));
                atomicAdd(a3 + 1, v3 * bfhi(h3));
            } else {
                for (int k = base; k < cnt; ++k) {
                    const int2 r0 = b[k];
                    const unsigned int h0 =
                        hw[(size_t)(r0.x & 0x7ffff) * 64 + lane];
                    const float v0 = __int_as_float(r0.y);
                    float* a0 = &accum[((r0.x >> 19) & 63) * OUT + 2 * lane];
                    atomicAdd(a0,     v0 * bflo(h0));
                    atomicAdd(a0 + 1, v0 * bfhi(h0));
                }
            }
        }
    }
    __syncthreads();

    // writeout: thread t -> node t>>2, quarter t&3; 64B chunks per step
    const int n = tid >> 2, qd = tid & 3;
    const int node = bin * NPB + n;
    if (node < n_nodes) {
        float4* __restrict__ op = (float4*)(out + (size_t)node * OUT);
        const float4* ap = (const float4*)&accum[n * OUT];
        #pragma unroll
        for (int i = 0; i < 8; ++i)
            op[i * 4 + qd] = ap[i * 4 + qd];
    }
}

// ---------------- legacy bucket fill (fallback paths) -----------------------
__global__ __launch_bounds__(256) void fill_kernel(
    const int* __restrict__ src, const int* __restrict__ dst,
    const float* __restrict__ vals, int* __restrict__ counts,
    int2* __restrict__ bucket, int4* __restrict__ spill,
    int* __restrict__ spill_cnt, int n_edges, int n_nodes,
    int cap, int spill_max)
{
    const int e = blockIdx.x * 256 + threadIdx.x;
    if (e >= n_edges) return;
    const size_t g = (size_t)blockIdx.y * n_edges + e;
    const int d = dst[g];
    const int enc = blockIdx.y * n_nodes + src[g];   // h row index
    const int pos = atomicAdd(&counts[d], 1);
    if (pos < cap) {
        bucket[(size_t)d * cap + pos] = make_int2(enc, __float_as_int(vals[g]));
    } else {
        const int sp = atomicAdd(spill_cnt, 1);
        if (sp < spill_max)
            spill[sp] = make_int4(d, enc, __float_as_int(vals[g]), 0);
    }
}

// ---------------- legacy gather (fallback paths) ----------------------------
__global__ __launch_bounds__(256) void gather_kernel(
    const unsigned short* __restrict__ h, const int2* __restrict__ bucket,
    const int* __restrict__ counts, float* __restrict__ out,
    int n_nodes, int cap, int accum)
{
    const int node = blockIdx.x * 8 + (threadIdx.x >> 5);
    const int lane = threadIdx.x & 31;
    if (node >= n_nodes) return;
    int cnt = counts[node];
    if (cnt > cap) cnt = cap;
    const int2* __restrict__ b = bucket + (size_t)node * cap;
    float4* __restrict__ op = (float4*)(out + (size_t)node * OUT);

    float4 acc = accum ? op[lane] : make_float4(0.f, 0.f, 0.f, 0.f);
    int j = 0;
    for (; j + 4 <= cnt; j += 4) {
        const int2 r0 = b[j], r1 = b[j + 1], r2 = b[j + 2], r3 = b[j + 3];
        const uint2 h0 = ((const uint2*)(h + (size_t)r0.x * OUT))[lane];
        const uint2 h1 = ((const uint2*)(h + (size_t)r1.x * OUT))[lane];
        const uint2 h2 = ((const uint2*)(h + (size_t)r2.x * OUT))[lane];
        const uint2 h3 = ((const uint2*)(h + (size_t)r3.x * OUT))[lane];
        const float v0 = __int_as_float(r0.y), v1 = __int_as_float(r1.y);
        const float v2 = __int_as_float(r2.y), v3 = __int_as_float(r3.y);
        acc.x += v0*bflo(h0.x) + v1*bflo(h1.x) + v2*bflo(h2.x) + v3*bflo(h3.x);
        acc.y += v0*bfhi(h0.x) + v1*bfhi(h1.x) + v2*bfhi(h2.x) + v3*bfhi(h3.x);
        acc.z += v0*bflo(h0.y) + v1*bflo(h1.y) + v2*bflo(h2.y) + v3*bflo(h3.y);
        acc.w += v0*bfhi(h0.y) + v1*bfhi(h1.y) + v2*bfhi(h2.y) + v3*bfhi(h3.y);
    }
    for (; j < cnt; ++j) {
        const int2 r0 = b[j];
        const float v = __int_as_float(r0.y);
        const uint2 hv = ((const uint2*)(h + (size_t)r0.x * OUT))[lane];
        acc.x += v * bflo(hv.x); acc.y += v * bfhi(hv.x);
        acc.z += v * bflo(hv.y); acc.w += v * bfhi(hv.y);
    }
    op[lane] = acc;
}

// ---------------- spill cleanup (expected ~0 edges) -------------------------
__global__ __launch_bounds__(256) void spill_kernel(
    const unsigned short* __restrict__ h, const int4* __restrict__ spill,
    const int* __restrict__ spill_cnt, float* __restrict__ out, int spill_max)
{
    int n = *spill_cnt;
    if (n > spill_max) n = spill_max;
    const int w = (blockIdx.x * 256 + threadIdx.x) >> 6;
    const int lane = threadIdx.x & 63;
    const int nw = gridDim.x * 4;
    for (int i = w; i < n; i += nw) {
        const int4 s = spill[i];
        const float v = __int_as_float(s.z);
        const unsigned int u = ((const unsigned int*)(h + (size_t)s.y * OUT))[lane];
        float* __restrict__ orow = out + (size_t)s.x * OUT;
        __hip_atomic_fetch_add(orow + lane * 2,     v * bflo(u),
                               __ATOMIC_RELAXED, __HIP_MEMORY_SCOPE_AGENT);
        __hip_atomic_fetch_add(orow + lane * 2 + 1, v * bfhi(u),
                               __ATOMIC_RELAXED, __HIP_MEMORY_SCOPE_AGENT);
    }
}

// ---------------- last-resort scatter (atomic, bf16 h, per relation) --------
__global__ __launch_bounds__(256) void scatter_kernel(
    const unsigned short* __restrict__ h, const int* __restrict__ src,
    const int* __restrict__ dst, const float* __restrict__ vals,
    float* __restrict__ out, int n_edges)
{
    const int e = blockIdx.x * 8 + (threadIdx.x >> 5);
    if (e >= n_edges) return;
    const int lane = threadIdx.x & 31;
    const int s = src[e];
    const int d = dst[e];
    const float v = vals[e];
    const unsigned int* __restrict__ hrow =
        (const unsigned int*)(h + (size_t)s * OUT);
    float* __restrict__ orow = out + (size_t)d * OUT;
    #pragma unroll
    for (int kk = 0; kk < 2; ++kk) {
        const int jj = lane + kk * 32;      // uint index: cols 2jj, 2jj+1
        const unsigned int u = hrow[jj];
        __hip_atomic_fetch_add(orow + jj * 2,     v * bflo(u),
                               __ATOMIC_RELAXED, __HIP_MEMORY_SCOPE_AGENT);
        __hip_atomic_fetch_add(orow + jj * 2 + 1, v * bfhi(u),
                               __ATOMIC_RELAXED, __HIP_MEMORY_SCOPE_AGENT);
    }
}

extern "C" void kernel_launch(void* const* d_in, const int* in_sizes, int n_in,
                              void* d_out, int out_size, void* d_ws, size_t ws_size,
                              hipStream_t stream) {
    const float* inp     = (const float*)d_in[0];
    const int*   src     = (const int*)  d_in[1];
    const int*   dst     = (const int*)  d_in[2];
    const float* vals    = (const float*)d_in[3];
    const float* weights = (const float*)d_in[4];
    float* out = (float*)d_out;

    const int n_nodes = in_sizes[0] / IN;            // 50000
    const int n_rel   = in_sizes[4] / (IN * OUT);    // 8
    const int n_edges = in_sizes[1] / n_rel;         // 100000

    auto align_up = [](size_t x) { return (x + 255) & ~(size_t)255; };
    const int SPILL_MAX = 65536;
    const size_t sz_inpb   = align_up((size_t)n_nodes * IN * 2);
    const size_t sz_wt     = align_up((size_t)n_rel * IN * OUT * 2);
    const size_t sz_spill  = align_up((size_t)SPILL_MAX * 16);

    const int conv_n8 = n_nodes * IN / 8;
    const int wt_tot  = n_rel * IN * OUT;
    const int gemm_gx = (n_nodes + 127) / 128;
    const int gath_gx = (n_nodes + 7) / 8;
    const int fill_gx = (n_edges + 255) / 256;
    const int nbins   = (n_nodes + NPB - 1) / NPB;

    // ---- primary path: XCD-local binning + fused gather ----
    if ((size_t)n_rel * n_nodes < (1u << 19)) {
        const size_t sz_h    = (size_t)n_rel * n_nodes * OUT * 2;
        const size_t sz_bcnt = align_up((size_t)(NXCD * nbins + 1) * 4);
        int cap = 0;
        const int caps[] = {256, 192};
        for (int c : caps) {
            const size_t sz_binned =
                align_up((size_t)NXCD * nbins * c * 8);
            if (sz_inpb + sz_wt + sz_bcnt + sz_spill + sz_h + sz_binned
                <= ws_size) { cap = c; break; }
        }
        if (cap > 0) {
            const size_t sz_binned = align_up((size_t)NXCD * nbins * cap * 8);
            char* p = (char*)d_ws;
            unsigned short* inpb = (unsigned short*)p;  p += sz_inpb;
            unsigned short* wtb  = (unsigned short*)p;  p += sz_wt;
            int*   bin_cnt = (int*)p;   p += sz_bcnt;
            int4*  spill   = (int4*)p;  p += sz_spill;
            unsigned short* h = (unsigned short*)p;     p += sz_h;
            int2*  binned  = (int2*)p;  p += sz_binned;
            int*   spill_cnt = bin_cnt + NXCD * nbins;

            conv_inp_kernel<<<(conv_n8 + 255) / 256, 256, 0, stream>>>(
                inp, inpb, conv_n8);
            conv_w_kernel<<<(wt_tot + 255) / 256, 256, 0, stream>>>(
                weights, wtb, wt_tot);
            hipMemsetAsync(bin_cnt, 0, (size_t)(NXCD * nbins + 1) * 4, stream);
            dim3 fg(fill_gx, n_rel);
            bin_fill_kernel<<<fg, 256, 0, stream>>>(src, dst, vals, bin_cnt,
                                                    binned, spill, spill_cnt,
                                                    n_edges, n_nodes, nbins,
                                                    cap, SPILL_MAX);
            dim3 gg(gemm_gx, n_rel);
            mfma_gemm<<<gg, 256, 0, stream>>>(inpb, wtb, h, 0, n_nodes);
            bin_agg_kernel<<<nbins, 256, 0, stream>>>(h, binned, bin_cnt, out,
                                                      n_nodes, nbins, cap);
            spill_kernel<<<128, 256, 0, stream>>>(h, spill, spill_cnt, out,
                                                  SPILL_MAX);
            return;
        }
    }

    const size_t sz_counts = align_up((size_t)(n_nodes + 1) * 4);
    const size_t fixed = sz_inpb + sz_wt + sz_counts + sz_spill;

    // ---- legacy full path: per-node buckets, all relations at once ----
    {
        const size_t sz_h = (size_t)n_rel * n_nodes * OUT * 2;
        int cap = 0;
        const int caps[] = {64, 48, 32, 24, 20};
        for (int c : caps) {
            if (fixed + sz_h + align_up((size_t)n_nodes * c * 8) <= ws_size) {
                cap = c; break;
            }
        }
        if (cap > 0) {
            char* p = (char*)d_ws;
            unsigned short* inpb = (unsigned short*)p;  p += sz_inpb;
            unsigned short* wtb  = (unsigned short*)p;  p += sz_wt;
            int*   counts = (int*)p;    p += sz_counts;
            int4*  spill  = (int4*)p;   p += sz_spill;
            unsigned short* h = (unsigned short*)p;     p += sz_h;
            int2*  bucket = (int2*)p;
            int*   spill_cnt = counts + n_nodes;

            conv_inp_kernel<<<(conv_n8 + 255) / 256, 256, 0, stream>>>(
                inp, inpb, conv_n8);
            conv_w_kernel<<<(wt_tot + 255) / 256, 256, 0, stream>>>(
                weights, wtb, wt_tot);
            hipMemsetAsync(counts, 0, (size_t)(n_nodes + 1) * 4, stream);
            dim3 fg(fill_gx, n_rel);
            fill_kernel<<<fg, 256, 0, stream>>>(src, dst, vals, counts, bucket,
                                                spill, spill_cnt, n_edges,
                                                n_nodes, cap, SPILL_MAX);
            dim3 gg(gemm_gx, n_rel);
            mfma_gemm<<<gg, 256, 0, stream>>>(inpb, wtb, h, 0, n_nodes);
            gather_kernel<<<gath_gx, 256, 0, stream>>>(h, bucket, counts, out,
                                                       n_nodes, cap, 0);
            spill_kernel<<<128, 256, 0, stream>>>(h, spill, spill_cnt, out,
                                                  SPILL_MAX);
            return;
        }
    }

    // ---- per-relation path ----
    {
        const size_t sz_h = (size_t)n_nodes * OUT * 2;
        int cap = 0;
        const int caps[] = {16, 12, 8};
        for (int c : caps) {
            if (fixed + sz_h + align_up((size_t)n_nodes * c * 8) <= ws_size) {
                cap = c; break;
            }
        }
        if (cap > 0) {
            char* p = (char*)d_ws;
            unsigned short* inpb = (unsigned short*)p;  p += sz_inpb;
            unsigned short* wtb  = (unsigned short*)p;  p += sz_wt;
            int*   counts = (int*)p;    p += sz_counts;
            int4*  spill  = (int4*)p;   p += sz_spill;
            unsigned short* h = (unsigned short*)p;     p += sz_h;
            int2*  bucket = (int2*)p;
            int*   spill_cnt = counts + n_nodes;

            conv_inp_kernel<<<(conv_n8 + 255) / 256, 256, 0, stream>>>(
                inp, inpb, conv_n8);
            conv_w_kernel<<<(wt_tot + 255) / 256, 256, 0, stream>>>(
                weights, wtb, wt_tot);
            for (int r = 0; r < n_rel; ++r) {
                const size_t eoff = (size_t)r * n_edges;
                hipMemsetAsync(counts, 0, (size_t)(n_nodes + 1) * 4, stream);
                dim3 fg(fill_gx, 1);
                fill_kernel<<<fg, 256, 0, stream>>>(src + eoff, dst + eoff,
                                                    vals + eoff, counts, bucket,
                                                    spill, spill_cnt, n_edges,
                                                    n_nodes, cap, SPILL_MAX);
                dim3 gg(gemm_gx, 1);
                mfma_gemm<<<gg, 256, 0, stream>>>(inpb, wtb, h, r, n_nodes);
                gather_kernel<<<gath_gx, 256, 0, stream>>>(h, bucket, counts,
                                                           out, n_nodes, cap,
                                                           r > 0 ? 1 : 0);
                spill_kernel<<<128, 256, 0, stream>>>(h, spill, spill_cnt, out,
                                                      SPILL_MAX);
            }
            return;
        }
    }

    // ---- last resort: per-relation gemm + atomic scatter ----
    {
        char* p = (char*)d_ws;
        unsigned short* inpb = (unsigned short*)p;  p += sz_inpb;
        unsigned short* wtb  = (unsigned short*)p;  p += sz_wt;
        unsigned short* h = (unsigned short*)p;

        conv_inp_kernel<<<(conv_n8 + 255) / 256, 256, 0, stream>>>(
            inp, inpb, conv_n8);
        conv_w_kernel<<<(wt_tot + 255) / 256, 256, 0, stream>>>(
            weights, wtb, wt_tot);
        hipMemsetAsync(out, 0, (size_t)n_nodes * OUT * 4, stream);
        const int sgx = (n_edges + 7) / 8;
        for (int r = 0; r < n_rel; ++r) {
            const size_t eoff = (size_t)r * n_edges;
            dim3 gg(gemm_gx, 1);
            mfma_gemm<<<gg, 256, 0, stream>>>(inpb, wtb, h, r, n_nodes);
            scatter_kernel<<<sgx, 256, 0, stream>>>(h, src + eoff, dst + eoff,
                                                    vals + eoff, out, n_edges);
        }
    }
}

// Round 2
// 231.737 us; speedup vs baseline: 3.7377x; 3.7377x over previous
//
#include <hip/hip_runtime.h>

// GCN layer: out = sum_r segment_sum(vals_r * inp[src_r], dst_r) @ W_r
// Round 6: keep XCD-local bin fill (fixed the 51 MB scattered writebacks),
// replace the LDS-atomic bin aggregator (683 us, latency-starved, 782 blocks)
// with LDS-CSR + per-node REGISTER accumulation at high TLP:
// 16 nodes/block (grid 3128), block builds a tiny LDS-CSR of its nodes'
// entries, then each 32-lane half-wave gathers 2 nodes with 4-deep ILP
// h-row loads and float4 register accumulation (round-4 gather structure).
// N=50000, R=8, E=100000, IN=OUT=128.

constexpr int IN  = 128;
constexpr int OUT = 128;
constexpr int LDK = 136;   // padded LDS row (bf16 elems) = 272 B
constexpr int NPB = 64;    // nodes per bin (binning path)
constexpr int NPBLK = 16;  // nodes per agg block
constexpr int MAXE = 2048; // max entries one agg block can own (= NXCD*cap)
constexpr int NXCD = 8;

typedef __attribute__((ext_vector_type(8))) short bf16x8;
typedef __attribute__((ext_vector_type(4))) float f32x4;

__device__ inline unsigned short f2bf(float f) {
    unsigned int u = __float_as_uint(f);
    u += 0x7fffu + ((u >> 16) & 1u);          // RNE
    return (unsigned short)(u >> 16);
}
__device__ inline float bflo(unsigned int u) { return __uint_as_float(u << 16); }
__device__ inline float bfhi(unsigned int u) { return __uint_as_float(u & 0xffff0000u); }

// ---------------- converts --------------------------------------------------
__global__ __launch_bounds__(256) void conv_inp_kernel(
    const float* __restrict__ x, unsigned short* __restrict__ y, int n8)
{
    const int i = blockIdx.x * 256 + threadIdx.x;
    if (i >= n8) return;
    const float4 a = ((const float4*)x)[i * 2];
    const float4 b = ((const float4*)x)[i * 2 + 1];
    uint4 o;
    o.x = (unsigned)f2bf(a.x) | ((unsigned)f2bf(a.y) << 16);
    o.y = (unsigned)f2bf(a.z) | ((unsigned)f2bf(a.w) << 16);
    o.z = (unsigned)f2bf(b.x) | ((unsigned)f2bf(b.y) << 16);
    o.w = (unsigned)f2bf(b.z) | ((unsigned)f2bf(b.w) << 16);
    ((uint4*)y)[i] = o;
}

// Wt[r][n][k] = W[r][k][n], bf16
__global__ __launch_bounds__(256) void conv_w_kernel(
    const float* __restrict__ w, unsigned short* __restrict__ wt, int total)
{
    const int t = blockIdx.x * 256 + threadIdx.x;
    if (t >= total) return;
    const int r = t >> 14, rem = t & 16383;
    const int n = rem >> 7, k = rem & 127;
    wt[t] = f2bf(w[(r << 14) + (k << 7) + n]);
}

// ---------------- MFMA GEMM: h[rel] = inp @ W[rel] --------------------------
__global__ __launch_bounds__(256) void mfma_gemm(
    const unsigned short* __restrict__ inpb,
    const unsigned short* __restrict__ wt,
    unsigned short* __restrict__ h, int rel_base, int n_nodes)
{
    __shared__ unsigned short As[128 * LDK];   // 34 KB

    const int rel = rel_base + blockIdx.y;
    const int row0 = blockIdx.x * 128;
    const int tid = threadIdx.x;
    const int wave = tid >> 6, lane = tid & 63;
    const int m = lane & 15, q = lane >> 4;

    // stage A: thread t -> row t/2, half-row (t&1)*64 elems (128 B)
    {
        const int r = tid >> 1;
        const int half = (tid & 1) * 64;
        const int grow = row0 + r;
        const uint4* gp = (const uint4*)(inpb + (size_t)grow * IN + half);
        uint4* lp = (uint4*)&As[r * LDK + half];
        #pragma unroll
        for (int i = 0; i < 8; ++i) {
            uint4 v = make_uint4(0u, 0u, 0u, 0u);
            if (grow < n_nodes) v = gp[i];
            lp[i] = v;
        }
    }

    // B fragments: b[nt][ks][j] = Wt[rel][n0+m][ks*32+q*8+j]
    bf16x8 bfrag[2][4];
    {
        const unsigned short* wtr = wt + ((size_t)rel * OUT + wave * 32) * IN;
        #pragma unroll
        for (int nt = 0; nt < 2; ++nt)
            #pragma unroll
            for (int ks = 0; ks < 4; ++ks)
                bfrag[nt][ks] = *(const bf16x8*)(
                    wtr + (size_t)(nt * 16 + m) * IN + ks * 32 + q * 8);
    }

    __syncthreads();

    f32x4 acc[8][2];
    #pragma unroll
    for (int mt = 0; mt < 8; ++mt)
        #pragma unroll
        for (int nt = 0; nt < 2; ++nt)
            acc[mt][nt] = (f32x4){0.f, 0.f, 0.f, 0.f};

    #pragma unroll
    for (int ks = 0; ks < 4; ++ks) {
        bf16x8 a[8];
        #pragma unroll
        for (int mt = 0; mt < 8; ++mt)
            a[mt] = *(const bf16x8*)&As[(mt * 16 + m) * LDK + ks * 32 + q * 8];
        #pragma unroll
        for (int mt = 0; mt < 8; ++mt) {
            acc[mt][0] = __builtin_amdgcn_mfma_f32_16x16x32_bf16(
                a[mt], bfrag[0][ks], acc[mt][0], 0, 0, 0);
            acc[mt][1] = __builtin_amdgcn_mfma_f32_16x16x32_bf16(
                a[mt], bfrag[1][ks], acc[mt][1], 0, 0, 0);
        }
    }

    unsigned short* hrel = h + (size_t)blockIdx.y * n_nodes * OUT;
    #pragma unroll
    for (int mt = 0; mt < 8; ++mt) {
        #pragma unroll
        for (int rg = 0; rg < 4; ++rg) {
            const int row = row0 + mt * 16 + q * 4 + rg;
            if (row < n_nodes) {
                unsigned short* hp = hrel + (size_t)row * OUT + wave * 32 + m;
                hp[0]  = f2bf(acc[mt][0][rg]);
                hp[16] = f2bf(acc[mt][1][rg]);
            }
        }
    }
}

// ---------------- XCD-local bin fill ----------------------------------------
// Bins of NPB=64 dst-nodes; 8 per-XCD copies so append tail lines stay in one
// L2 (sequential appends -> full line utilization).
// entry.x = (dst&63)<<19 | (rel*n_nodes+src)   [needs n_rel*n_nodes < 2^19]
// entry.y = val bits
__global__ __launch_bounds__(256) void bin_fill_kernel(
    const int* __restrict__ src, const int* __restrict__ dst,
    const float* __restrict__ vals, int* __restrict__ bin_cnt,
    int2* __restrict__ binned, int4* __restrict__ spill,
    int* __restrict__ spill_cnt, int n_edges, int n_nodes,
    int nbins, int cap, int spill_max)
{
    int xcd;
    asm volatile("s_getreg_b32 %0, hwreg(HW_REG_XCC_ID)" : "=s"(xcd));
    xcd &= (NXCD - 1);
    const int e = blockIdx.x * 256 + threadIdx.x;
    if (e >= n_edges) return;
    const size_t g = (size_t)blockIdx.y * n_edges + e;
    const int d = dst[g];
    const int enc = blockIdx.y * n_nodes + src[g];
    const int bin = d >> 6;                       // NPB = 64
    const int packed = ((d & 63) << 19) | enc;
    const int cell = xcd * nbins + bin;
    const int pos = atomicAdd(&bin_cnt[cell], 1);
    if (pos < cap) {
        binned[(size_t)cell * cap + pos] =
            make_int2(packed, __float_as_int(vals[g]));
    } else {
        const int sp = atomicAdd(spill_cnt, 1);
        if (sp < spill_max)
            spill[sp] = make_int4(d, enc, __float_as_int(vals[g]), 0);
    }
}

// ---------------- bin aggregate v2: LDS-CSR + register gather ---------------
// Block owns NPBLK=16 nodes of one bin. Scans the bin's 8 XCD cells
// (coalesced), builds an LDS-CSR of entries for its nodes, then each 32-lane
// half-wave gathers 2 nodes: 4-deep ILP h-row loads, float4 register acc,
// single coalesced 512 B store per node. No LDS atomics on the hot path.
__global__ __launch_bounds__(256) void bin_agg2_kernel(
    const unsigned short* __restrict__ h, const int2* __restrict__ binned,
    const int* __restrict__ bin_cnt, float* __restrict__ out,
    int n_nodes, int nbins, int cap)
{
    __shared__ int2 sorted[MAXE];               // 16 KB
    __shared__ int lcnt[NPBLK], loff[NPBLK], lcur[NPBLK];
    __shared__ int cellcnt[NXCD];

    const int bin = blockIdx.x >> 2;
    const int nlo = (blockIdx.x & 3) * NPBLK;   // local node base within bin
    const int tid = threadIdx.x;

    if (tid < NPBLK) lcnt[tid] = 0;
    if (tid >= 32 && tid < 32 + NXCD) {
        int c = bin_cnt[(tid - 32) * nbins + bin];
        cellcnt[tid - 32] = c > cap ? cap : c;
    }
    __syncthreads();

    // pass 1: count entries per local node
    for (int xc = 0; xc < NXCD; ++xc) {
        const int cnt = cellcnt[xc];
        const int2* __restrict__ b = binned + (size_t)(xc * nbins + bin) * cap;
        for (int i = tid; i < cnt; i += 256) {
            const int ln = ((b[i].x >> 19) & 63) - nlo;
            if ((unsigned)ln < (unsigned)NPBLK) atomicAdd(&lcnt[ln], 1);
        }
    }
    __syncthreads();
    if (tid == 0) {
        int s = 0;
        #pragma unroll
        for (int i = 0; i < NPBLK; ++i) { loff[i] = s; s += lcnt[i]; }
    }
    if (tid < NPBLK) lcur[tid] = 0;
    __syncthreads();

    // pass 2: place entries (cells are L2-hot after pass 1)
    for (int xc = 0; xc < NXCD; ++xc) {
        const int cnt = cellcnt[xc];
        const int2* __restrict__ b = binned + (size_t)(xc * nbins + bin) * cap;
        for (int i = tid; i < cnt; i += 256) {
            const int2 e = b[i];
            const int ln = ((e.x >> 19) & 63) - nlo;
            if ((unsigned)ln < (unsigned)NPBLK) {
                const int pos = atomicAdd(&lcur[ln], 1);
                sorted[loff[ln] + pos] = e;
            }
        }
    }
    __syncthreads();

    // gather: half-wave hw handles local nodes 2*hw, 2*hw+1
    const int hw = tid >> 5, lane = tid & 31;
    #pragma unroll
    for (int k = 0; k < 2; ++k) {
        const int ln = hw * 2 + k;
        const int node = bin * NPB + nlo + ln;
        if (node >= n_nodes) continue;
        const int base = loff[ln];
        const int cnt  = lcnt[ln];
        float4 acc = make_float4(0.f, 0.f, 0.f, 0.f);
        int j = 0;
        for (; j + 4 <= cnt; j += 4) {
            const int2 r0 = sorted[base + j],     r1 = sorted[base + j + 1];
            const int2 r2 = sorted[base + j + 2], r3 = sorted[base + j + 3];
            const uint2 h0 = ((const uint2*)(h + (size_t)(r0.x & 0x7ffff) * OUT))[lane];
            const uint2 h1 = ((const uint2*)(h + (size_t)(r1.x & 0x7ffff) * OUT))[lane];
            const uint2 h2 = ((const uint2*)(h + (size_t)(r2.x & 0x7ffff) * OUT))[lane];
            const uint2 h3 = ((const uint2*)(h + (size_t)(r3.x & 0x7ffff) * OUT))[lane];
            const float v0 = __int_as_float(r0.y), v1 = __int_as_float(r1.y);
            const float v2 = __int_as_float(r2.y), v3 = __int_as_float(r3.y);
            acc.x += v0*bflo(h0.x) + v1*bflo(h1.x) + v2*bflo(h2.x) + v3*bflo(h3.x);
            acc.y += v0*bfhi(h0.x) + v1*bfhi(h1.x) + v2*bfhi(h2.x) + v3*bfhi(h3.x);
            acc.z += v0*bflo(h0.y) + v1*bflo(h1.y) + v2*bflo(h2.y) + v3*bflo(h3.y);
            acc.w += v0*bfhi(h0.y) + v1*bfhi(h1.y) + v2*bfhi(h2.y) + v3*bfhi(h3.y);
        }
        for (; j < cnt; ++j) {
            const int2 r0 = sorted[base + j];
            const float v = __int_as_float(r0.y);
            const uint2 hv = ((const uint2*)(h + (size_t)(r0.x & 0x7ffff) * OUT))[lane];
            acc.x += v * bflo(hv.x); acc.y += v * bfhi(hv.x);
            acc.z += v * bflo(hv.y); acc.w += v * bfhi(hv.y);
        }
        ((float4*)(out + (size_t)node * OUT))[lane] = acc;
    }
}

// ---------------- legacy bucket fill (fallback paths) -----------------------
__global__ __launch_bounds__(256) void fill_kernel(
    const int* __restrict__ src, const int* __restrict__ dst,
    const float* __restrict__ vals, int* __restrict__ counts,
    int2* __restrict__ bucket, int4* __restrict__ spill,
    int* __restrict__ spill_cnt, int n_edges, int n_nodes,
    int cap, int spill_max)
{
    const int e = blockIdx.x * 256 + threadIdx.x;
    if (e >= n_edges) return;
    const size_t g = (size_t)blockIdx.y * n_edges + e;
    const int d = dst[g];
    const int enc = blockIdx.y * n_nodes + src[g];   // h row index
    const int pos = atomicAdd(&counts[d], 1);
    if (pos < cap) {
        bucket[(size_t)d * cap + pos] = make_int2(enc, __float_as_int(vals[g]));
    } else {
        const int sp = atomicAdd(spill_cnt, 1);
        if (sp < spill_max)
            spill[sp] = make_int4(d, enc, __float_as_int(vals[g]), 0);
    }
}

// ---------------- legacy gather (fallback paths) ----------------------------
__global__ __launch_bounds__(256) void gather_kernel(
    const unsigned short* __restrict__ h, const int2* __restrict__ bucket,
    const int* __restrict__ counts, float* __restrict__ out,
    int n_nodes, int cap, int accum)
{
    const int node = blockIdx.x * 8 + (threadIdx.x >> 5);
    const int lane = threadIdx.x & 31;
    if (node >= n_nodes) return;
    int cnt = counts[node];
    if (cnt > cap) cnt = cap;
    const int2* __restrict__ b = bucket + (size_t)node * cap;
    float4* __restrict__ op = (float4*)(out + (size_t)node * OUT);

    float4 acc = accum ? op[lane] : make_float4(0.f, 0.f, 0.f, 0.f);
    int j = 0;
    for (; j + 4 <= cnt; j += 4) {
        const int2 r0 = b[j], r1 = b[j + 1], r2 = b[j + 2], r3 = b[j + 3];
        const uint2 h0 = ((const uint2*)(h + (size_t)r0.x * OUT))[lane];
        const uint2 h1 = ((const uint2*)(h + (size_t)r1.x * OUT))[lane];
        const uint2 h2 = ((const uint2*)(h + (size_t)r2.x * OUT))[lane];
        const uint2 h3 = ((const uint2*)(h + (size_t)r3.x * OUT))[lane];
        const float v0 = __int_as_float(r0.y), v1 = __int_as_float(r1.y);
        const float v2 = __int_as_float(r2.y), v3 = __int_as_float(r3.y);
        acc.x += v0*bflo(h0.x) + v1*bflo(h1.x) + v2*bflo(h2.x) + v3*bflo(h3.x);
        acc.y += v0*bfhi(h0.x) + v1*bfhi(h1.x) + v2*bfhi(h2.x) + v3*bfhi(h3.x);
        acc.z += v0*bflo(h0.y) + v1*bflo(h1.y) + v2*bflo(h2.y) + v3*bflo(h3.y);
        acc.w += v0*bfhi(h0.y) + v1*bfhi(h1.y) + v2*bfhi(h2.y) + v3*bfhi(h3.y);
    }
    for (; j < cnt; ++j) {
        const int2 r0 = b[j];
        const float v = __int_as_float(r0.y);
        const uint2 hv = ((const uint2*)(h + (size_t)r0.x * OUT))[lane];
        acc.x += v * bflo(hv.x); acc.y += v * bfhi(hv.x);
        acc.z += v * bflo(hv.y); acc.w += v * bfhi(hv.y);
    }
    op[lane] = acc;
}

// ---------------- spill cleanup (expected ~0 edges) -------------------------
__global__ __launch_bounds__(256) void spill_kernel(
    const unsigned short* __restrict__ h, const int4* __restrict__ spill,
    const int* __restrict__ spill_cnt, float* __restrict__ out, int spill_max)
{
    int n = *spill_cnt;
    if (n > spill_max) n = spill_max;
    const int w = (blockIdx.x * 256 + threadIdx.x) >> 6;
    const int lane = threadIdx.x & 63;
    const int nw = gridDim.x * 4;
    for (int i = w; i < n; i += nw) {
        const int4 s = spill[i];
        const float v = __int_as_float(s.z);
        const unsigned int u = ((const unsigned int*)(h + (size_t)s.y * OUT))[lane];
        float* __restrict__ orow = out + (size_t)s.x * OUT;
        __hip_atomic_fetch_add(orow + lane * 2,     v * bflo(u),
                               __ATOMIC_RELAXED, __HIP_MEMORY_SCOPE_AGENT);
        __hip_atomic_fetch_add(orow + lane * 2 + 1, v * bfhi(u),
                               __ATOMIC_RELAXED, __HIP_MEMORY_SCOPE_AGENT);
    }
}

// ---------------- last-resort scatter (atomic, bf16 h, per relation) --------
__global__ __launch_bounds__(256) void scatter_kernel(
    const unsigned short* __restrict__ h, const int* __restrict__ src,
    const int* __restrict__ dst, const float* __restrict__ vals,
    float* __restrict__ out, int n_edges)
{
    const int e = blockIdx.x * 8 + (threadIdx.x >> 5);
    if (e >= n_edges) return;
    const int lane = threadIdx.x & 31;
    const int s = src[e];
    const int d = dst[e];
    const float v = vals[e];
    const unsigned int* __restrict__ hrow =
        (const unsigned int*)(h + (size_t)s * OUT);
    float* __restrict__ orow = out + (size_t)d * OUT;
    #pragma unroll
    for (int kk = 0; kk < 2; ++kk) {
        const int jj = lane + kk * 32;      // uint index: cols 2jj, 2jj+1
        const unsigned int u = hrow[jj];
        __hip_atomic_fetch_add(orow + jj * 2,     v * bflo(u),
                               __ATOMIC_RELAXED, __HIP_MEMORY_SCOPE_AGENT);
        __hip_atomic_fetch_add(orow + jj * 2 + 1, v * bfhi(u),
                               __ATOMIC_RELAXED, __HIP_MEMORY_SCOPE_AGENT);
    }
}

extern "C" void kernel_launch(void* const* d_in, const int* in_sizes, int n_in,
                              void* d_out, int out_size, void* d_ws, size_t ws_size,
                              hipStream_t stream) {
    const float* inp     = (const float*)d_in[0];
    const int*   src     = (const int*)  d_in[1];
    const int*   dst     = (const int*)  d_in[2];
    const float* vals    = (const float*)d_in[3];
    const float* weights = (const float*)d_in[4];
    float* out = (float*)d_out;

    const int n_nodes = in_sizes[0] / IN;            // 50000
    const int n_rel   = in_sizes[4] / (IN * OUT);    // 8
    const int n_edges = in_sizes[1] / n_rel;         // 100000

    auto align_up = [](size_t x) { return (x + 255) & ~(size_t)255; };
    const int SPILL_MAX = 65536;
    const size_t sz_inpb   = align_up((size_t)n_nodes * IN * 2);
    const size_t sz_wt     = align_up((size_t)n_rel * IN * OUT * 2);
    const size_t sz_spill  = align_up((size_t)SPILL_MAX * 16);

    const int conv_n8 = n_nodes * IN / 8;
    const int wt_tot  = n_rel * IN * OUT;
    const int gemm_gx = (n_nodes + 127) / 128;
    const int gath_gx = (n_nodes + 7) / 8;
    const int fill_gx = (n_edges + 255) / 256;
    const int nbins   = (n_nodes + NPB - 1) / NPB;

    // ---- primary path: XCD-local binning + LDS-CSR register gather ----
    if ((size_t)n_rel * n_nodes < (1u << 19)) {
        const size_t sz_h    = (size_t)n_rel * n_nodes * OUT * 2;
        const size_t sz_bcnt = align_up((size_t)(NXCD * nbins + 1) * 4);
        int cap = 0;
        const int caps[] = {256, 192};
        for (int c : caps) {
            const size_t sz_binned =
                align_up((size_t)NXCD * nbins * c * 8);
            if (sz_inpb + sz_wt + sz_bcnt + sz_spill + sz_h + sz_binned
                <= ws_size) { cap = c; break; }
        }
        if (cap > 0) {
            const size_t sz_binned = align_up((size_t)NXCD * nbins * cap * 8);
            char* p = (char*)d_ws;
            unsigned short* inpb = (unsigned short*)p;  p += sz_inpb;
            unsigned short* wtb  = (unsigned short*)p;  p += sz_wt;
            int*   bin_cnt = (int*)p;   p += sz_bcnt;
            int4*  spill   = (int4*)p;  p += sz_spill;
            unsigned short* h = (unsigned short*)p;     p += sz_h;
            int2*  binned  = (int2*)p;  p += sz_binned;
            int*   spill_cnt = bin_cnt + NXCD * nbins;

            conv_inp_kernel<<<(conv_n8 + 255) / 256, 256, 0, stream>>>(
                inp, inpb, conv_n8);
            conv_w_kernel<<<(wt_tot + 255) / 256, 256, 0, stream>>>(
                weights, wtb, wt_tot);
            hipMemsetAsync(bin_cnt, 0, (size_t)(NXCD * nbins + 1) * 4, stream);
            dim3 fg(fill_gx, n_rel);
            bin_fill_kernel<<<fg, 256, 0, stream>>>(src, dst, vals, bin_cnt,
                                                    binned, spill, spill_cnt,
                                                    n_edges, n_nodes, nbins,
                                                    cap, SPILL_MAX);
            dim3 gg(gemm_gx, n_rel);
            mfma_gemm<<<gg, 256, 0, stream>>>(inpb, wtb, h, 0, n_nodes);
            bin_agg2_kernel<<<nbins * (NPB / NPBLK), 256, 0, stream>>>(
                h, binned, bin_cnt, out, n_nodes, nbins, cap);
            spill_kernel<<<128, 256, 0, stream>>>(h, spill, spill_cnt, out,
                                                  SPILL_MAX);
            return;
        }
    }

    const size_t sz_counts = align_up((size_t)(n_nodes + 1) * 4);
    const size_t fixed = sz_inpb + sz_wt + sz_counts + sz_spill;

    // ---- legacy full path: per-node buckets, all relations at once ----
    {
        const size_t sz_h = (size_t)n_rel * n_nodes * OUT * 2;
        int cap = 0;
        const int caps[] = {64, 48, 32, 24, 20};
        for (int c : caps) {
            if (fixed + sz_h + align_up((size_t)n_nodes * c * 8) <= ws_size) {
                cap = c; break;
            }
        }
        if (cap > 0) {
            char* p = (char*)d_ws;
            unsigned short* inpb = (unsigned short*)p;  p += sz_inpb;
            unsigned short* wtb  = (unsigned short*)p;  p += sz_wt;
            int*   counts = (int*)p;    p += sz_counts;
            int4*  spill  = (int4*)p;   p += sz_spill;
            unsigned short* h = (unsigned short*)p;     p += sz_h;
            int2*  bucket = (int2*)p;
            int*   spill_cnt = counts + n_nodes;

            conv_inp_kernel<<<(conv_n8 + 255) / 256, 256, 0, stream>>>(
                inp, inpb, conv_n8);
            conv_w_kernel<<<(wt_tot + 255) / 256, 256, 0, stream>>>(
                weights, wtb, wt_tot);
            hipMemsetAsync(counts, 0, (size_t)(n_nodes + 1) * 4, stream);
            dim3 fg(fill_gx, n_rel);
            fill_kernel<<<fg, 256, 0, stream>>>(src, dst, vals, counts, bucket,
                                                spill, spill_cnt, n_edges,
                                                n_nodes, cap, SPILL_MAX);
            dim3 gg(gemm_gx, n_rel);
            mfma_gemm<<<gg, 256, 0, stream>>>(inpb, wtb, h, 0, n_nodes);
            gather_kernel<<<gath_gx, 256, 0, stream>>>(h, bucket, counts, out,
                                                       n_nodes, cap, 0);
            spill_kernel<<<128, 256, 0, stream>>>(h, spill, spill_cnt, out,
                                                  SPILL_MAX);
            return;
        }
    }

    // ---- per-relation path ----
    {
        const size_t sz_h = (size_t)n_nodes * OUT * 2;
        int cap = 0;
        const int caps[] = {16, 12, 8};
        for (int c : caps) {
            if (fixed + sz_h + align_up((size_t)n_nodes * c * 8) <= ws_size) {
                cap = c; break;
            }
        }
        if (cap > 0) {
            char* p = (char*)d_ws;
            unsigned short* inpb = (unsigned short*)p;  p += sz_inpb;
            unsigned short* wtb  = (unsigned short*)p;  p += sz_wt;
            int*   counts = (int*)p;    p += sz_counts;
            int4*  spill  = (int4*)p;   p += sz_spill;
            unsigned short* h = (unsigned short*)p;     p += sz_h;
            int2*  bucket = (int2*)p;
            int*   spill_cnt = counts + n_nodes;

            conv_inp_kernel<<<(conv_n8 + 255) / 256, 256, 0, stream>>>(
                inp, inpb, conv_n8);
            conv_w_kernel<<<(wt_tot + 255) / 256, 256, 0, stream>>>(
                weights, wtb, wt_tot);
            for (int r = 0; r < n_rel; ++r) {
                const size_t eoff = (size_t)r * n_edges;
                hipMemsetAsync(counts, 0, (size_t)(n_nodes + 1) * 4, stream);
                dim3 fg(fill_gx, 1);
                fill_kernel<<<fg, 256, 0, stream>>>(src + eoff, dst + eoff,
                                                    vals + eoff, counts, bucket,
                                                    spill, spill_cnt, n_edges,
                                                    n_nodes, cap, SPILL_MAX);
                dim3 gg(gemm_gx, 1);
                mfma_gemm<<<gg, 256, 0, stream>>>(inpb, wtb, h, r, n_nodes);
                gather_kernel<<<gath_gx, 256, 0, stream>>>(h, bucket, counts,
                                                           out, n_nodes, cap,
                                                           r > 0 ? 1 : 0);
                spill_kernel<<<128, 256, 0, stream>>>(h, spill, spill_cnt, out,
                                                      SPILL_MAX);
            }
            return;
        }
    }

    // ---- last resort: per-relation gemm + atomic scatter ----
    {
        char* p = (char*)d_ws;
        unsigned short* inpb = (unsigned short*)p;  p += sz_inpb;
        unsigned short* wtb  = (unsigned short*)p;  p += sz_wt;
        unsigned short* h = (unsigned short*)p;

        conv_inp_kernel<<<(conv_n8 + 255) / 256, 256, 0, stream>>>(
            inp, inpb, conv_n8);
        conv_w_kernel<<<(wt_tot + 255) / 256, 256, 0, stream>>>(
            weights, wtb, wt_tot);
        hipMemsetAsync(out, 0, (size_t)n_nodes * OUT * 4, stream);
        const int sgx = (n_edges + 7) / 8;
        for (int r = 0; r < n_rel; ++r) {
            const size_t eoff = (size_t)r * n_edges;
            dim3 gg(gemm_gx, 1);
            mfma_gemm<<<gg, 256, 0, stream>>>(inpb, wtb, h, r, n_nodes);
            scatter_kernel<<<sgx, 256, 0, stream>>>(h, src + eoff, dst + eoff,
                                                    vals + eoff, out, n_edges);
        }
    }
}